// Round 6
// baseline (181.844 us; speedup 1.0000x reference)
//
#include <hip/hip_runtime.h>
#include <stdint.h>

#define T 49
#define CCH 256

typedef __bf16 bf16x8 __attribute__((ext_vector_type(8)));
typedef float f32x4 __attribute__((ext_vector_type(4)));

static __device__ __forceinline__ unsigned short f2bf(float f){
  __bf16 h = (__bf16)f;                       // compiler emits v_cvt_pk_bf16_f32 pairs
  return __builtin_bit_cast(unsigned short, h);
}
static __device__ __forceinline__ float bf2f(unsigned short h){
  return __builtin_bit_cast(float, ((uint32_t)h) << 16);
}
static __device__ __forceinline__ uint32_t pk2(float a, float b){
  return (uint32_t)f2bf(a) | ((uint32_t)f2bf(b) << 16);
}
static __device__ __forceinline__ f32x4 mfma16(bf16x8 a, bf16x8 b, f32x4 c){
  return __builtin_amdgcn_mfma_f32_16x16x32_bf16(a, b, c, 0, 0, 0);
}
// XOR-swizzle of 16B chunks within 128B, keyed by low 3 bits of the row index.
#define SWZ(row) ((((row) & 7) << 4))

// Build an MFMA A/B-frag (lane: n/m=lo, k=8g+e) from packed C-layout words.
static __device__ __forceinline__ bf16x8 build_frag(uint32_t lo_w0, uint32_t lo_w1,
                                                    uint32_t hi_w0, uint32_t hi_w1,
                                                    int srcA, int srcB, bool use_hi){
  uint32_t a0 = (uint32_t)__shfl((int)lo_w0, srcA, 64);
  uint32_t c0 = (uint32_t)__shfl((int)hi_w0, srcA, 64);
  uint32_t a1 = (uint32_t)__shfl((int)lo_w1, srcA, 64);
  uint32_t c1 = (uint32_t)__shfl((int)hi_w1, srcA, 64);
  uint32_t a2 = (uint32_t)__shfl((int)lo_w0, srcB, 64);
  uint32_t c2 = (uint32_t)__shfl((int)hi_w0, srcB, 64);
  uint32_t a3 = (uint32_t)__shfl((int)lo_w1, srcB, 64);
  uint32_t c3 = (uint32_t)__shfl((int)hi_w1, srcB, 64);
  uint4 u = use_hi ? make_uint4(c0, c1, c2, c3) : make_uint4(a0, a1, a2, a3);
  return __builtin_bit_cast(bf16x8, u);
}

// ---------------- prep kernels ----------------

__global__ void prep_wqkvT(const float* __restrict__ wq, const float* __restrict__ wk,
                           const float* __restrict__ wv, unsigned short* __restrict__ out){
  int bk = blockIdx.x;            // 0..767
  int p = bk >> 8, kk = bk & 255;
  int n = threadIdx.x;
  const float* w = (p == 0) ? wq : (p == 1 ? wk : wv);
  float scl = (p == 0) ? 0.17677669529663687f : 1.0f;
  out[(size_t)(p * 256 + n) * 256 + kk] = f2bf(w[kk * 256 + n] * scl);
}

__global__ void prep_wodT(const float* __restrict__ wo, const float* __restrict__ dw,
                          unsigned short* __restrict__ out){
  int hd = blockIdx.x;            // 0..255
  int c = threadIdx.x;            // 0..255
  float s = 0.f;
  for (int cp = 0; cp < 256; ++cp) s = fmaf(wo[hd * 256 + cp], dw[cp * 256 + c], s);
  out[(size_t)c * 256 + hd] = f2bf(s);
}

// block 0: bqkv (q-scaled) + bod
// blocks 1..8: biasP[h*4096 + jt*1024 + nt*256 + g*64 + lo*4 + r] = bias(j=16jt+4g+r, i=16nt+lo)
__global__ void prep_misc(const int* __restrict__ rp, const float* __restrict__ btab,
                          const float* __restrict__ bq, const float* __restrict__ bk,
                          const float* __restrict__ bv, const float* __restrict__ bo,
                          const float* __restrict__ dwm, const float* __restrict__ db,
                          unsigned short* __restrict__ biasP, float* __restrict__ bqkv,
                          float* __restrict__ bod){
  int t = threadIdx.x;
  if (blockIdx.x == 0){
    for (int idx = t; idx < 768; idx += 256){
      int p = idx >> 8, n = idx & 255;
      float v = (p == 0) ? bq[n] * 0.17677669529663687f : (p == 1 ? bk[n] : bv[n]);
      bqkv[idx] = v;
    }
    float s = db[t];
    for (int cp = 0; cp < 256; ++cp) s = fmaf(bo[cp], dwm[cp * 256 + t], s);
    bod[t] = s;
  } else {
    int h = blockIdx.x - 1;
    for (int idx = t; idx < 4096; idx += 256){
      int r  = idx & 3;
      int lo = (idx >> 2) & 15;
      int g  = (idx >> 6) & 3;
      int nt = (idx >> 8) & 3;
      int jt = idx >> 10;
      int j = 16 * jt + 4 * g + r;
      int i = 16 * nt + lo;
      float v;
      if (j >= T) v = -1e30f;
      else if (i >= T) v = 0.f;
      else {
        int r0 = rp[i * 49 + j];
        int r1 = rp[2401 + i * 49 + j];
        v = btab[h * 169 + r0 * 13 + r1];
      }
      biasP[h * 4096 + idx] = f2bf(v);
    }
  }
}

// ---------------- fused main kernel ----------------
// 1 block = 1 window, 1024 threads = 16 waves = 2 waves per head (wave w: head
// w>>1, token-half w&1). q/k/v staged in LDS (round-2 layout, 144 KB, 1
// block/CU anyway at 16 waves). Per-wave chains halved vs 8-wave version;
// peak regs ~48 AGPR + ~45 VGPR -> fits 128-reg budget with no spill.
__launch_bounds__(1024, 4)
__global__ void wmsa_main(const float* __restrict__ x,
                          const unsigned short* __restrict__ wqkvT,
                          const unsigned short* __restrict__ wodT,
                          const unsigned short* __restrict__ biasP,
                          const float* __restrict__ bqkv,
                          const float* __restrict__ bod,
                          float* __restrict__ y){
  __shared__ unsigned short xs[64 * 256];      // 32 KB (reused for 'out')
  __shared__ unsigned short qs[8 * 64 * 40];   // 40 KB
  __shared__ unsigned short ksh[8 * 64 * 40];  // 40 KB
  __shared__ unsigned short vts[8 * 32 * 64];  // 32 KB

  const int b    = blockIdx.x;
  const int tid  = threadIdx.x;
  const int w    = tid >> 6;
  const int h    = w >> 1;         // head
  const int half = w & 1;          // token-half of this head
  const int lane = tid & 63;
  const int g    = lane >> 4;
  const int lo   = lane & 15;
  char* xs_c = (char*)xs;

  // ---- stage x -> xs (fp32->bf16, zero pad rows >= 49, swizzled) ----
  const float* xb = x + (size_t)b * T * CCH;
  #pragma unroll
  for (int idx = tid; idx < 64 * 64; idx += 1024){
    int row = idx >> 6, c4 = idx & 63;
    float4 v = make_float4(0.f, 0.f, 0.f, 0.f);
    if (row < T) v = reinterpret_cast<const float4*>(xb)[row * 64 + c4];
    *reinterpret_cast<uint2*>(xs_c + row * 512 + ((c4 * 8) ^ SWZ(row)))
        = make_uint2(pk2(v.x, v.y), pk2(v.z, v.w));
  }
  __syncthreads();

  // ---- QKV: wave (h,half) computes rows 32*half..+31 of q,k,v for head h ----
  {
    f32x4 acc[2][6];
    #pragma unroll
    for (int mt = 0; mt < 2; ++mt)
      #pragma unroll
      for (int s = 0; s < 6; ++s) acc[mt][s] = f32x4{0,0,0,0};

    #pragma unroll 1
    for (int kt = 0; kt < 8; ++kt){
      bf16x8 a[2];
      #pragma unroll
      for (int mt = 0; mt < 2; ++mt){
        int row = 16 * (2 * half + mt) + lo;
        a[mt] = *reinterpret_cast<const bf16x8*>(xs_c + row * 512 + ((kt * 64 + 16 * g) ^ SWZ(row)));
      }
      #pragma unroll
      for (int s = 0; s < 6; ++s){
        int p = s >> 1, ntl = s & 1;
        int nrow = p * 256 + h * 32 + ntl * 16 + lo;
        const bf16x8 bfr = *reinterpret_cast<const bf16x8*>(
            wqkvT + (size_t)nrow * 256 + kt * 32 + 8 * g);
        #pragma unroll
        for (int mt = 0; mt < 2; ++mt) acc[mt][s] = mfma16(a[mt], bfr, acc[mt][s]);
      }
    }
    // epilogue: +bias; q,k -> [t][d] stride 40; v -> transposed+swizzled [d][t]
    #pragma unroll
    for (int s = 0; s < 6; ++s){
      int p = s >> 1, ntl = s & 1;
      int d = ntl * 16 + lo;
      float bias = bqkv[p * 256 + h * 32 + d];
      #pragma unroll
      for (int mt = 0; mt < 2; ++mt){
        int mtg = 2 * half + mt;
        f32x4 t = acc[mt][s];
        if (p < 2){
          unsigned short* dst = (p == 0 ? qs : ksh) + h * 2560;
          #pragma unroll
          for (int r = 0; r < 4; ++r)
            dst[(16 * mtg + 4 * g + r) * 40 + d] = f2bf(t[r] + bias);
        } else {
          *reinterpret_cast<uint2*>((char*)vts + h * 4096 + d * 128 + ((mtg * 32 + g * 8) ^ SWZ(d)))
              = make_uint2(pk2(t[0] + bias, t[1] + bias), pk2(t[2] + bias, t[3] + bias));
        }
      }
    }
  }
  __syncthreads();   // q/k/v visible to both waves of each head; xs now dead

  // ---- attention: wave (h,half) handles i-columns nt in {2*half, 2*half+1} ----
  const char* qb = (const char*)qs + h * 5120;
  const char* kb = (const char*)ksh + h * 5120;
  const char* vb = (const char*)vts + h * 4096;
  const int  src_lo = lo + 32 * (g & 1);
  const int  src_hi = src_lo + 16;
  const bool ghi    = (g >= 2);

  bf16x8 ak[4], bq_[2];
  #pragma unroll
  for (int jt = 0; jt < 4; ++jt)
    ak[jt] = *reinterpret_cast<const bf16x8*>(kb + (16 * jt + lo) * 80 + 16 * g);
  #pragma unroll
  for (int ntl = 0; ntl < 2; ++ntl){
    int nt = 2 * half + ntl;
    bq_[ntl] = *reinterpret_cast<const bf16x8*>(qb + (16 * nt + lo) * 80 + 16 * g);
  }

  // QK^T + bias
  f32x4 lacc[4][2];
  #pragma unroll
  for (int jt = 0; jt < 4; ++jt)
    #pragma unroll
    for (int ntl = 0; ntl < 2; ++ntl){
      lacc[jt][ntl] = mfma16(ak[jt], bq_[ntl], f32x4{0,0,0,0});
      int nt = 2 * half + ntl;
      const uint2 bb = *reinterpret_cast<const uint2*>(
          biasP + h * 4096 + jt * 1024 + nt * 256 + (g * 16 + lo) * 4);
      lacc[jt][ntl][0] += bf2f((unsigned short)(bb.x & 0xffff));
      lacc[jt][ntl][1] += bf2f((unsigned short)(bb.x >> 16));
      lacc[jt][ntl][2] += bf2f((unsigned short)(bb.y & 0xffff));
      lacc[jt][ntl][3] += bf2f((unsigned short)(bb.y >> 16));
    }

  // softmax over j per column i, then PV and out write (streamed per ntl)
  #pragma unroll
  for (int ntl = 0; ntl < 2; ++ntl){
    float m = -3.0e38f;
    #pragma unroll
    for (int jt = 0; jt < 4; ++jt)
      #pragma unroll
      for (int r = 0; r < 4; ++r) m = fmaxf(m, lacc[jt][ntl][r]);
    m = fmaxf(m, __shfl_xor(m, 16, 64));
    m = fmaxf(m, __shfl_xor(m, 32, 64));
    float ssum = 0.f;
    uint32_t pw[4][2];
    #pragma unroll
    for (int jt = 0; jt < 4; ++jt){
      f32x4 t = lacc[jt][ntl];
      #pragma unroll
      for (int r = 0; r < 4; ++r){
        t[r] = exp2f((t[r] - m) * 1.4426950408889634f);
        ssum += t[r];
      }
      pw[jt][0] = pk2(t[0], t[1]);
      pw[jt][1] = pk2(t[2], t[3]);
    }
    ssum += __shfl_xor(ssum, 16, 64);
    ssum += __shfl_xor(ssum, 32, 64);
    const float r0 = 1.f / ssum;

    bf16x8 pf0 = build_frag(pw[0][0], pw[0][1], pw[1][0], pw[1][1], src_lo, src_hi, ghi);
    bf16x8 pf1 = build_frag(pw[2][0], pw[2][1], pw[3][0], pw[3][1], src_lo, src_hi, ghi);

    const int nt = 2 * half + ntl;
    const int i  = 16 * nt + lo;
    #pragma unroll
    for (int dt = 0; dt < 2; ++dt){
      int row = 16 * dt + lo;
      bf16x8 av0 = *reinterpret_cast<const bf16x8*>(vb + row * 128 + ((16 * g) ^ SWZ(row)));
      bf16x8 av1 = *reinterpret_cast<const bf16x8*>(vb + row * 128 + ((64 + 16 * g) ^ SWZ(row)));
      f32x4 oacc = mfma16(av0, pf0, f32x4{0,0,0,0});
      oacc = mfma16(av1, pf1, oacc);
      *reinterpret_cast<uint2*>(xs_c + i * 512 + ((h * 64 + dt * 32 + g * 8) ^ SWZ(i)))
          = make_uint2(pk2(oacc[0] * r0, oacc[1] * r0), pk2(oacc[2] * r0, oacc[3] * r0));
    }
  }
  __syncthreads();

  // ---- final GEMM: y[i][c] = sum_hd out[i][hd] * wodT[c][hd] + bod[c] ----
  f32x4 facc[2][2];
  #pragma unroll
  for (int mt = 0; mt < 2; ++mt)
    #pragma unroll
    for (int ntl = 0; ntl < 2; ++ntl) facc[mt][ntl] = f32x4{0,0,0,0};

  #pragma unroll 1
  for (int kt = 0; kt < 8; ++kt){
    bf16x8 a[2];
    #pragma unroll
    for (int mt = 0; mt < 2; ++mt){
      int row = 16 * (2 * half + mt) + lo;
      a[mt] = *reinterpret_cast<const bf16x8*>(xs_c + row * 512 + ((kt * 64 + 16 * g) ^ SWZ(row)));
    }
    #pragma unroll
    for (int ntl = 0; ntl < 2; ++ntl){
      int crow = h * 32 + ntl * 16 + lo;
      const bf16x8 bfr = *reinterpret_cast<const bf16x8*>(wodT + (size_t)crow * 256 + kt * 32 + 8 * g);
      #pragma unroll
      for (int mt = 0; mt < 2; ++mt) facc[mt][ntl] = mfma16(a[mt], bfr, facc[mt][ntl]);
    }
  }
  #pragma unroll
  for (int ntl = 0; ntl < 2; ++ntl){
    int c = h * 32 + ntl * 16 + lo;
    float bd = bod[c];
    #pragma unroll
    for (int mt = 0; mt < 2; ++mt)
      #pragma unroll
      for (int r = 0; r < 4; ++r){
        int i = 16 * (2 * half + mt) + 4 * g + r;
        if (i < T) y[((size_t)b * T + i) * CCH + c] = facc[mt][ntl][r] + bd;
      }
  }
}

// ---------------- launch ----------------
extern "C" void kernel_launch(void* const* d_in, const int* in_sizes, int n_in,
                              void* d_out, int out_size, void* d_ws, size_t ws_size,
                              hipStream_t stream){
  const float* x    = (const float*)d_in[0];
  const int*   rp   = (const int*)d_in[1];
  const float* btab = (const float*)d_in[2];
  const float* wq   = (const float*)d_in[3];
  const float* bq   = (const float*)d_in[4];
  const float* wk   = (const float*)d_in[5];
  const float* bk   = (const float*)d_in[6];
  const float* wv   = (const float*)d_in[7];
  const float* bv   = (const float*)d_in[8];
  const float* wo   = (const float*)d_in[9];
  const float* bo   = (const float*)d_in[10];
  const float* dw   = (const float*)d_in[11];
  const float* db   = (const float*)d_in[12];
  float* y = (float*)d_out;

  char* ws = (char*)d_ws;
  unsigned short* wqkvT = (unsigned short*)(ws);            // 393216 B
  unsigned short* wodT  = (unsigned short*)(ws + 393216);   // 131072 B
  unsigned short* biasP = (unsigned short*)(ws + 524288);   // 65536 B
  float* bqkv           = (float*)(ws + 589824);            // 3072 B
  float* bod            = (float*)(ws + 592896);            // 1024 B

  prep_wqkvT<<<768, 256, 0, stream>>>(wq, wk, wv, wqkvT);
  prep_wodT<<<256, 256, 0, stream>>>(wo, dw, wodT);
  prep_misc<<<9, 256, 0, stream>>>(rp, btab, bq, bk, bv, bo, dw, db, biasP, bqkv, bod);
  wmsa_main<<<1024, 1024, 0, stream>>>(x, wqkvT, wodT, biasP, bqkv, bod, y);
}

// Round 7
// 134.249 us; speedup vs baseline: 1.3545x; 1.3545x over previous
//
#include <hip/hip_runtime.h>
#include <stdint.h>

#define T 49
#define CCH 256

typedef __bf16 bf16x8 __attribute__((ext_vector_type(8)));
typedef float f32x4 __attribute__((ext_vector_type(4)));

static __device__ __forceinline__ unsigned short f2bf(float f){
  __bf16 h = (__bf16)f;
  return __builtin_bit_cast(unsigned short, h);
}
static __device__ __forceinline__ float bf2f(unsigned short h){
  return __builtin_bit_cast(float, ((uint32_t)h) << 16);
}
static __device__ __forceinline__ uint32_t pk2(float a, float b){
  return (uint32_t)f2bf(a) | ((uint32_t)f2bf(b) << 16);
}
static __device__ __forceinline__ f32x4 mfma16(bf16x8 a, bf16x8 b, f32x4 c){
  return __builtin_amdgcn_mfma_f32_16x16x32_bf16(a, b, c, 0, 0, 0);
}
// XOR-swizzle of 16B chunks within 128B, keyed by low 3 bits of the row index.
#define SWZ(row) ((((row) & 7) << 4))

// Build an MFMA A/B-frag (lane: n/m=lo, k=8g+e) from packed C-layout words.
static __device__ __forceinline__ bf16x8 build_frag(uint32_t lo_w0, uint32_t lo_w1,
                                                    uint32_t hi_w0, uint32_t hi_w1,
                                                    int srcA, int srcB, bool use_hi){
  uint32_t a0 = (uint32_t)__shfl((int)lo_w0, srcA, 64);
  uint32_t c0 = (uint32_t)__shfl((int)hi_w0, srcA, 64);
  uint32_t a1 = (uint32_t)__shfl((int)lo_w1, srcA, 64);
  uint32_t c1 = (uint32_t)__shfl((int)hi_w1, srcA, 64);
  uint32_t a2 = (uint32_t)__shfl((int)lo_w0, srcB, 64);
  uint32_t c2 = (uint32_t)__shfl((int)hi_w0, srcB, 64);
  uint32_t a3 = (uint32_t)__shfl((int)lo_w1, srcB, 64);
  uint32_t c3 = (uint32_t)__shfl((int)hi_w1, srcB, 64);
  uint4 u = use_hi ? make_uint4(c0, c1, c2, c3) : make_uint4(a0, a1, a2, a3);
  return __builtin_bit_cast(bf16x8, u);
}

// ---------------- prep kernels ----------------

__global__ void prep_wqkvT(const float* __restrict__ wq, const float* __restrict__ wk,
                           const float* __restrict__ wv, unsigned short* __restrict__ out){
  int bk = blockIdx.x;            // 0..767
  int p = bk >> 8, kk = bk & 255;
  int n = threadIdx.x;
  const float* w = (p == 0) ? wq : (p == 1 ? wk : wv);
  float scl = (p == 0) ? 0.17677669529663687f : 1.0f;
  out[(size_t)(p * 256 + n) * 256 + kk] = f2bf(w[kk * 256 + n] * scl);
}

__global__ void prep_wodT(const float* __restrict__ wo, const float* __restrict__ dw,
                          unsigned short* __restrict__ out){
  int hd = blockIdx.x;            // 0..255
  int c = threadIdx.x;            // 0..255
  float s = 0.f;
  for (int cp = 0; cp < 256; ++cp) s = fmaf(wo[hd * 256 + cp], dw[cp * 256 + c], s);
  out[(size_t)c * 256 + hd] = f2bf(s);
}

// block 0: bqkv (q-scaled) + bod
// blocks 1..8: biasP[h*4096 + jt*1024 + nt*256 + g*64 + lo*4 + r] = bias(j=16jt+4g+r, i=16nt+lo)
__global__ void prep_misc(const int* __restrict__ rp, const float* __restrict__ btab,
                          const float* __restrict__ bq, const float* __restrict__ bk,
                          const float* __restrict__ bv, const float* __restrict__ bo,
                          const float* __restrict__ dwm, const float* __restrict__ db,
                          unsigned short* __restrict__ biasP, float* __restrict__ bqkv,
                          float* __restrict__ bod){
  int t = threadIdx.x;
  if (blockIdx.x == 0){
    for (int idx = t; idx < 768; idx += 256){
      int p = idx >> 8, n = idx & 255;
      float v = (p == 0) ? bq[n] * 0.17677669529663687f : (p == 1 ? bk[n] : bv[n]);
      bqkv[idx] = v;
    }
    float s = db[t];
    for (int cp = 0; cp < 256; ++cp) s = fmaf(bo[cp], dwm[cp * 256 + t], s);
    bod[t] = s;
  } else {
    int h = blockIdx.x - 1;
    for (int idx = t; idx < 4096; idx += 256){
      int r  = idx & 3;
      int lo = (idx >> 2) & 15;
      int g  = (idx >> 6) & 3;
      int nt = (idx >> 8) & 3;
      int jt = idx >> 10;
      int j = 16 * jt + 4 * g + r;
      int i = 16 * nt + lo;
      float v;
      if (j >= T) v = -1e30f;
      else if (i >= T) v = 0.f;
      else {
        int r0 = rp[i * 49 + j];
        int r1 = rp[2401 + i * 49 + j];
        v = btab[h * 169 + r0 * 13 + r1];
      }
      biasP[h * 4096 + idx] = f2bf(v);
    }
  }
}

// ---------------- fused main kernel ----------------
// 1 block = 1 window, 512 threads, wave = head. LDS: xs 32KB (reused for out)
// + vts 32KB (v staged, per-head, validated r1/r2/r6 layout) = 64KB -> 2
// blocks/CU. All memory streams issue-batched (4 kt-steps of weight frags in
// flight; staging loads 8-deep) to break per-iteration latency serialization.
__launch_bounds__(512, 4)
__global__ void wmsa_main(const float* __restrict__ x,
                          const unsigned short* __restrict__ wqkvT,
                          const unsigned short* __restrict__ wodT,
                          const unsigned short* __restrict__ biasP,
                          const float* __restrict__ bqkv,
                          const float* __restrict__ bod,
                          float* __restrict__ y){
  __shared__ unsigned short xs[64 * 256];      // 32 KB
  __shared__ unsigned short vts[8 * 32 * 64];  // 32 KB

  const int b    = blockIdx.x;
  const int tid  = threadIdx.x;
  const int h    = tid >> 6;       // wave == head
  const int lane = tid & 63;
  const int g    = lane >> 4;
  const int lo   = lane & 15;
  char* xs_c = (char*)xs;

  // ---- stage x -> xs: issue all 8 loads, then convert+write ----
  const float* xb = x + (size_t)b * T * CCH;
  {
    float4 vv[8];
    #pragma unroll
    for (int k2 = 0; k2 < 8; ++k2){
      int idx = tid + k2 * 512;
      int row = idx >> 6, c4 = idx & 63;
      vv[k2] = make_float4(0.f, 0.f, 0.f, 0.f);
      if (row < T) vv[k2] = reinterpret_cast<const float4*>(xb)[row * 64 + c4];
    }
    #pragma unroll
    for (int k2 = 0; k2 < 8; ++k2){
      int idx = tid + k2 * 512;
      int row = idx >> 6, c4 = idx & 63;
      *reinterpret_cast<uint2*>(xs_c + row * 512 + ((c4 * 8) ^ SWZ(row)))
          = make_uint2(pk2(vv[k2].x, vv[k2].y), pk2(vv[k2].z, vv[k2].w));
    }
  }
  __syncthreads();

  const int  srcA = lo + 16 * ((2 * g) & 3);
  const int  srcB = lo + 16 * ((2 * g + 1) & 3);
  const bool ghi  = (g >= 2);

  // ---- pass 1: v (normal GEMM) -> vts LDS [d][t] swizzled ----
  {
    f32x4 avc[4][2];
    #pragma unroll
    for (int mt = 0; mt < 4; ++mt)
      #pragma unroll
      for (int nt = 0; nt < 2; ++nt) avc[mt][nt] = f32x4{0,0,0,0};

    #pragma unroll 1
    for (int kb = 0; kb < 2; ++kb){
      bf16x8 wv[2][4];
      #pragma unroll
      for (int nt = 0; nt < 2; ++nt)
        #pragma unroll
        for (int q4 = 0; q4 < 4; ++q4)
          wv[nt][q4] = *reinterpret_cast<const bf16x8*>(
              wqkvT + (size_t)(512 + h * 32 + 16 * nt + lo) * 256 + (kb * 4 + q4) * 32 + 8 * g);
      #pragma unroll
      for (int q4 = 0; q4 < 4; ++q4){
        int kt = kb * 4 + q4;
        bf16x8 ax[4];
        #pragma unroll
        for (int mt = 0; mt < 4; ++mt){
          int row = 16 * mt + lo;
          ax[mt] = *reinterpret_cast<const bf16x8*>(xs_c + row * 512 + ((kt * 64 + 16 * g) ^ SWZ(row)));
        }
        #pragma unroll
        for (int nt = 0; nt < 2; ++nt)
          #pragma unroll
          for (int mt = 0; mt < 4; ++mt) avc[mt][nt] = mfma16(ax[mt], wv[nt][q4], avc[mt][nt]);
      }
    }
    // epilogue: +bias, store transposed+swizzled [d][t] (r1/r2/r6-validated)
    #pragma unroll
    for (int nt = 0; nt < 2; ++nt){
      const float bvs = bqkv[512 + h * 32 + 16 * nt + lo];
      const int d = 16 * nt + lo;
      #pragma unroll
      for (int mt = 0; mt < 4; ++mt){
        f32x4 t = avc[mt][nt];
        *reinterpret_cast<uint2*>((char*)vts + h * 4096 + d * 128 + ((mt * 32 + g * 8) ^ SWZ(d)))
            = make_uint2(pk2(t[0] + bvs, t[1] + bvs), pk2(t[2] + bvs, t[3] + bvs));
      }
    }
  }

  // ---- pass 2: k (transposed GEMM) -> fk frags ----
  bf16x8 fk[4];   // K A-frag (j=lo, d=8g+e)
  {
    f32x4 akk[2][4];
    #pragma unroll
    for (int mt = 0; mt < 2; ++mt)
      #pragma unroll
      for (int nt = 0; nt < 4; ++nt) akk[mt][nt] = f32x4{0,0,0,0};

    #pragma unroll 1
    for (int kb = 0; kb < 2; ++kb){
      bf16x8 wk[2][4];
      #pragma unroll
      for (int mt = 0; mt < 2; ++mt)
        #pragma unroll
        for (int q4 = 0; q4 < 4; ++q4)
          wk[mt][q4] = *reinterpret_cast<const bf16x8*>(
              wqkvT + (size_t)(256 + h * 32 + 16 * mt + lo) * 256 + (kb * 4 + q4) * 32 + 8 * g);
      #pragma unroll
      for (int q4 = 0; q4 < 4; ++q4){
        int kt = kb * 4 + q4;
        bf16x8 bx[4];
        #pragma unroll
        for (int nt = 0; nt < 4; ++nt){
          int row = 16 * nt + lo;
          bx[nt] = *reinterpret_cast<const bf16x8*>(xs_c + row * 512 + ((kt * 64 + 16 * g) ^ SWZ(row)));
        }
        #pragma unroll
        for (int mt = 0; mt < 2; ++mt)
          #pragma unroll
          for (int nt = 0; nt < 4; ++nt) akk[mt][nt] = mfma16(wk[mt][q4], bx[nt], akk[mt][nt]);
      }
    }
    uint32_t pkk[2][4][2];
    #pragma unroll
    for (int mt = 0; mt < 2; ++mt){
      const float4 b4k = *reinterpret_cast<const float4*>(bqkv + 256 + h * 32 + 16 * mt + 4 * g);
      #pragma unroll
      for (int nt = 0; nt < 4; ++nt){
        f32x4 tk = akk[mt][nt];
        tk[0] += b4k.x; tk[1] += b4k.y; tk[2] += b4k.z; tk[3] += b4k.w;
        pkk[mt][nt][0] = pk2(tk[0], tk[1]); pkk[mt][nt][1] = pk2(tk[2], tk[3]);
      }
    }
    #pragma unroll
    for (int nt = 0; nt < 4; ++nt)
      fk[nt] = build_frag(pkk[0][nt][0], pkk[0][nt][1], pkk[1][nt][0], pkk[1][nt][1], srcA, srcB, ghi);
  }

  // ---- pass 3: q (transposed GEMM) -> fq frags ----
  bf16x8 fq[4];   // Q B-frag (i=lo, d=8g+e)
  {
    f32x4 aq[2][4];
    #pragma unroll
    for (int mt = 0; mt < 2; ++mt)
      #pragma unroll
      for (int nt = 0; nt < 4; ++nt) aq[mt][nt] = f32x4{0,0,0,0};

    #pragma unroll 1
    for (int kb = 0; kb < 4; ++kb){
      bf16x8 wq2[2][2];
      #pragma unroll
      for (int mt = 0; mt < 2; ++mt)
        #pragma unroll
        for (int q2 = 0; q2 < 2; ++q2)
          wq2[mt][q2] = *reinterpret_cast<const bf16x8*>(
              wqkvT + (size_t)(h * 32 + 16 * mt + lo) * 256 + (kb * 2 + q2) * 32 + 8 * g);
      #pragma unroll
      for (int q2 = 0; q2 < 2; ++q2){
        int kt = kb * 2 + q2;
        bf16x8 bx[4];
        #pragma unroll
        for (int nt = 0; nt < 4; ++nt){
          int row = 16 * nt + lo;
          bx[nt] = *reinterpret_cast<const bf16x8*>(xs_c + row * 512 + ((kt * 64 + 16 * g) ^ SWZ(row)));
        }
        #pragma unroll
        for (int mt = 0; mt < 2; ++mt)
          #pragma unroll
          for (int nt = 0; nt < 4; ++nt) aq[mt][nt] = mfma16(wq2[mt][q2], bx[nt], aq[mt][nt]);
      }
    }
    uint32_t pq[2][4][2];
    #pragma unroll
    for (int mt = 0; mt < 2; ++mt){
      const float4 b4q = *reinterpret_cast<const float4*>(bqkv + h * 32 + 16 * mt + 4 * g);
      #pragma unroll
      for (int nt = 0; nt < 4; ++nt){
        f32x4 tq = aq[mt][nt];
        tq[0] += b4q.x; tq[1] += b4q.y; tq[2] += b4q.z; tq[3] += b4q.w;
        pq[mt][nt][0] = pk2(tq[0], tq[1]); pq[mt][nt][1] = pk2(tq[2], tq[3]);
      }
    }
    #pragma unroll
    for (int nt = 0; nt < 4; ++nt)
      fq[nt] = build_frag(pq[0][nt][0], pq[0][nt][1], pq[1][nt][0], pq[1][nt][1], srcA, srcB, ghi);
  }
  __syncthreads();   // all xs reads done; attention overwrites xs with 'out'

  // ---- streamed attention: per i-column-tile nt: QK^T -> softmax -> PV ----
  const char* vb = (const char*)vts + h * 4096;
  #pragma unroll 1
  for (int nt = 0; nt < 4; ++nt){
    uint2 bb[4];
    #pragma unroll
    for (int jt = 0; jt < 4; ++jt)
      bb[jt] = *reinterpret_cast<const uint2*>(
          biasP + h * 4096 + jt * 1024 + nt * 256 + (g * 16 + lo) * 4);
    f32x4 lacc[4];
    #pragma unroll
    for (int jt = 0; jt < 4; ++jt){
      lacc[jt] = mfma16(fk[jt], fq[nt], f32x4{0,0,0,0});
      lacc[jt][0] += bf2f((unsigned short)(bb[jt].x & 0xffff));
      lacc[jt][1] += bf2f((unsigned short)(bb[jt].x >> 16));
      lacc[jt][2] += bf2f((unsigned short)(bb[jt].y & 0xffff));
      lacc[jt][3] += bf2f((unsigned short)(bb[jt].y >> 16));
    }
    float m = -3.0e38f;
    #pragma unroll
    for (int jt = 0; jt < 4; ++jt)
      #pragma unroll
      for (int r = 0; r < 4; ++r) m = fmaxf(m, lacc[jt][r]);
    m = fmaxf(m, __shfl_xor(m, 16, 64));
    m = fmaxf(m, __shfl_xor(m, 32, 64));
    float ssum = 0.f;
    uint32_t pw[4][2];
    #pragma unroll
    for (int jt = 0; jt < 4; ++jt){
      f32x4 t = lacc[jt];
      #pragma unroll
      for (int r = 0; r < 4; ++r){
        t[r] = exp2f((t[r] - m) * 1.4426950408889634f);
        ssum += t[r];
      }
      pw[jt][0] = pk2(t[0], t[1]);
      pw[jt][1] = pk2(t[2], t[3]);
    }
    ssum += __shfl_xor(ssum, 16, 64);
    ssum += __shfl_xor(ssum, 32, 64);
    const float r0 = 1.f / ssum;

    bf16x8 pf0 = build_frag(pw[0][0], pw[0][1], pw[1][0], pw[1][1], srcA, srcB, ghi);
    bf16x8 pf1 = build_frag(pw[2][0], pw[2][1], pw[3][0], pw[3][1], srcA, srcB, ghi);

    const int i = 16 * nt + lo;
    #pragma unroll
    for (int dt = 0; dt < 2; ++dt){
      int row = 16 * dt + lo;
      bf16x8 av0 = *reinterpret_cast<const bf16x8*>(vb + row * 128 + ((16 * g) ^ SWZ(row)));
      bf16x8 av1 = *reinterpret_cast<const bf16x8*>(vb + row * 128 + ((64 + 16 * g) ^ SWZ(row)));
      f32x4 oacc = mfma16(av0, pf0, f32x4{0,0,0,0});
      oacc = mfma16(av1, pf1, oacc);
      *reinterpret_cast<uint2*>(xs_c + i * 512 + ((h * 64 + dt * 32 + g * 8) ^ SWZ(i)))
          = make_uint2(pk2(oacc[0] * r0, oacc[1] * r0), pk2(oacc[2] * r0, oacc[3] * r0));
    }
  }
  __syncthreads();

  // ---- final GEMM: y[i][c] = sum_hd out[i][hd] * wodT[c][hd] + bod[c] ----
  f32x4 facc[4][2];
  #pragma unroll
  for (int mt = 0; mt < 4; ++mt)
    #pragma unroll
    for (int nt = 0; nt < 2; ++nt) facc[mt][nt] = f32x4{0,0,0,0};

  #pragma unroll 1
  for (int kb = 0; kb < 2; ++kb){
    bf16x8 wod[2][4];
    #pragma unroll
    for (int nt = 0; nt < 2; ++nt)
      #pragma unroll
      for (int q4 = 0; q4 < 4; ++q4)
        wod[nt][q4] = *reinterpret_cast<const bf16x8*>(
            wodT + (size_t)(h * 32 + nt * 16 + lo) * 256 + (kb * 4 + q4) * 32 + 8 * g);
    #pragma unroll
    for (int q4 = 0; q4 < 4; ++q4){
      int kt = kb * 4 + q4;
      bf16x8 a[4];
      #pragma unroll
      for (int mt = 0; mt < 4; ++mt){
        int row = 16 * mt + lo;
        a[mt] = *reinterpret_cast<const bf16x8*>(xs_c + row * 512 + ((kt * 64 + 16 * g) ^ SWZ(row)));
      }
      #pragma unroll
      for (int nt = 0; nt < 2; ++nt)
        #pragma unroll
        for (int mt = 0; mt < 4; ++mt) facc[mt][nt] = mfma16(a[mt], wod[nt][q4], facc[mt][nt]);
    }
  }
  #pragma unroll
  for (int nt = 0; nt < 2; ++nt){
    int c = h * 32 + nt * 16 + lo;
    float bd = bod[c];
    #pragma unroll
    for (int mt = 0; mt < 4; ++mt)
      #pragma unroll
      for (int r = 0; r < 4; ++r){
        int i = 16 * mt + 4 * g + r;
        if (i < T) y[((size_t)b * T + i) * CCH + c] = facc[mt][nt][r] + bd;
      }
  }
}

// ---------------- launch ----------------
extern "C" void kernel_launch(void* const* d_in, const int* in_sizes, int n_in,
                              void* d_out, int out_size, void* d_ws, size_t ws_size,
                              hipStream_t stream){
  const float* x    = (const float*)d_in[0];
  const int*   rp   = (const int*)d_in[1];
  const float* btab = (const float*)d_in[2];
  const float* wq   = (const float*)d_in[3];
  const float* bq   = (const float*)d_in[4];
  const float* wk   = (const float*)d_in[5];
  const float* bk   = (const float*)d_in[6];
  const float* wv   = (const float*)d_in[7];
  const float* bv   = (const float*)d_in[8];
  const float* wo   = (const float*)d_in[9];
  const float* bo   = (const float*)d_in[10];
  const float* dw   = (const float*)d_in[11];
  const float* db   = (const float*)d_in[12];
  float* y = (float*)d_out;

  char* ws = (char*)d_ws;
  unsigned short* wqkvT = (unsigned short*)(ws);            // 393216 B
  unsigned short* wodT  = (unsigned short*)(ws + 393216);   // 131072 B
  unsigned short* biasP = (unsigned short*)(ws + 524288);   // 65536 B
  float* bqkv           = (float*)(ws + 589824);            // 3072 B
  float* bod            = (float*)(ws + 592896);            // 1024 B

  prep_wqkvT<<<768, 256, 0, stream>>>(wq, wk, wv, wqkvT);
  prep_wodT<<<256, 256, 0, stream>>>(wo, dw, wodT);
  prep_misc<<<9, 256, 0, stream>>>(rp, btab, bq, bk, bv, bo, dw, db, biasP, bqkv, bod);
  wmsa_main<<<1024, 512, 0, stream>>>(x, wqkvT, wodT, biasP, bqkv, bod, y);
}